// Round 1
// baseline (1452.733 us; speedup 1.0000x reference)
//
#include <hip/hip_runtime.h>
#include <math.h>

// Build CSR row offsets from the sorted self_fea_idx.
// row_start[j] = first edge whose segment id >= j ; row_start[N] = M.
__global__ void build_row_start(const int* __restrict__ self_idx,
                                int* __restrict__ row_start, int M, int N) {
  int i = blockIdx.x * blockDim.x + threadIdx.x;
  if (i >= M) return;
  int cur = self_idx[i];
  int prev = (i == 0) ? -1 : self_idx[i - 1];
  for (int j = prev + 1; j <= cur; ++j) row_start[j] = i;
  if (i == M - 1) {
    for (int j = cur + 1; j <= N; ++j) row_start[j] = M;
  }
}

// One wave (64 lanes) per segment. lane = output feature dim d.
// Each lane holds W1[:,d] (128 f32) and W2[:,d] (64 f32) in registers.
// Online-softmax attention pooling: MLP evaluated exactly once per edge,
// no [M,64] intermediate ever hits memory.
__global__ __launch_bounds__(64, 2)
void fused_message_pool(const float* __restrict__ atom_w,
                        const float* __restrict__ atom_fea,
                        const int* __restrict__ nbr_idx,
                        const float* __restrict__ W1,
                        const float* __restrict__ b1,
                        const float* __restrict__ W2,
                        const float* __restrict__ b2,
                        const float* __restrict__ Wg,
                        const float* __restrict__ bg,
                        const int* __restrict__ row_start,
                        float* __restrict__ out, int N) {
  const int lane = threadIdx.x;

  // Per-lane weight columns in registers (static indexing -> SROA to VGPRs).
  float w1r[128];
  float w2r[64];
#pragma unroll
  for (int k = 0; k < 128; ++k) w1r[k] = W1[k * 64 + lane];
#pragma unroll
  for (int j = 0; j < 64; ++j) w2r[j] = W2[j * 64 + lane];
  const float b1r = b1[lane];
  const float b2r = b2[lane];
  const float wgr = Wg[lane];
  const float bgs = bg[0];

  __shared__ float xsbuf[64];
  __shared__ float xnbuf[64];
  __shared__ float hbuf[64];

  for (int s = blockIdx.x; s < N; s += gridDim.x) {
    const int start = row_start[s];
    const int end = row_start[s + 1];
    const float xs = atom_fea[(size_t)s * 64 + lane];

    __syncthreads();           // WAR vs previous segment's LDS reads
    xsbuf[lane] = xs;          // self row staged once per segment

    float m = -INFINITY;       // running max
    float ssum = 0.f;          // running denom
    float acc = 0.f;           // running weighted sum (this lane's dim)

    for (int e = start; e < end; ++e) {
      const int nb = nbr_idx[e];
      const float xn = atom_fea[(size_t)nb * 64 + lane];
      const float awn = atom_w[nb];

      __syncthreads();         // WAR for xnbuf; also publishes xsbuf (1st iter)
      xnbuf[lane] = xn;
      __syncthreads();

      // ---- layer 1: h[d] = leaky( sum_k x[k]*W1[k][d] + b1[d] ) ----
      float a0 = 0.f, a1 = 0.f, a2 = 0.f, a3 = 0.f;
      const float4* xv = (const float4*)xsbuf;   // broadcast reads
#pragma unroll
      for (int k4 = 0; k4 < 16; ++k4) {
        float4 x4 = xv[k4];
        a0 = fmaf(x4.x, w1r[4 * k4 + 0], a0);
        a1 = fmaf(x4.y, w1r[4 * k4 + 1], a1);
        a2 = fmaf(x4.z, w1r[4 * k4 + 2], a2);
        a3 = fmaf(x4.w, w1r[4 * k4 + 3], a3);
      }
      const float4* xnv = (const float4*)xnbuf;
#pragma unroll
      for (int k4 = 0; k4 < 16; ++k4) {
        float4 x4 = xnv[k4];
        a0 = fmaf(x4.x, w1r[64 + 4 * k4 + 0], a0);
        a1 = fmaf(x4.y, w1r[64 + 4 * k4 + 1], a1);
        a2 = fmaf(x4.z, w1r[64 + 4 * k4 + 2], a2);
        a3 = fmaf(x4.w, w1r[64 + 4 * k4 + 3], a3);
      }
      float h = (a0 + a1) + (a2 + a3) + b1r;
      h = (h > 0.f) ? h : 0.01f * h;   // jax.nn.leaky_relu default slope

      __syncthreads();         // WAR for hbuf
      hbuf[lane] = h;
      __syncthreads();

      // ---- layer 2: F[d] = sum_j h[j]*W2[j][d] + b2[d] ----
      float c0 = 0.f, c1 = 0.f, c2 = 0.f, c3 = 0.f;
      const float4* hv = (const float4*)hbuf;
#pragma unroll
      for (int j4 = 0; j4 < 16; ++j4) {
        float4 h4 = hv[j4];
        c0 = fmaf(h4.x, w2r[4 * j4 + 0], c0);
        c1 = fmaf(h4.y, w2r[4 * j4 + 1], c1);
        c2 = fmaf(h4.z, w2r[4 * j4 + 2], c2);
        c3 = fmaf(h4.w, w2r[4 * j4 + 3], c3);
      }
      const float F = (c0 + c1) + (c2 + c3) + b2r;

      // ---- gate = sum_d F[d]*Wg[d] + bg  (butterfly -> all lanes same g) ----
      float g = F * wgr;
#pragma unroll
      for (int off = 1; off < 64; off <<= 1) g += __shfl_xor(g, off);
      g += bgs;

      // ---- online softmax update ----
      if (g > m) {
        const float f = expf(m - g);   // m=-inf on first edge -> f=0
        acc *= f;
        ssum *= f;
        m = g;
      }
      const float w = awn * expf(g - m);
      ssum += w;
      acc = fmaf(w, F, acc);
    }

    out[(size_t)s * 64 + lane] = acc / (ssum + 1e-13f) + xs;
  }
}

extern "C" void kernel_launch(void* const* d_in, const int* in_sizes, int n_in,
                              void* d_out, int out_size, void* d_ws, size_t ws_size,
                              hipStream_t stream) {
  const float* atom_w   = (const float*)d_in[0];
  const float* atom_fea = (const float*)d_in[1];
  const int*   self_idx = (const int*)d_in[2];
  const int*   nbr_idx  = (const int*)d_in[3];
  const float* W1 = (const float*)d_in[4];
  const float* b1 = (const float*)d_in[5];
  const float* W2 = (const float*)d_in[6];
  const float* b2 = (const float*)d_in[7];
  const float* Wg = (const float*)d_in[8];
  const float* bg = (const float*)d_in[9];
  float* out = (float*)d_out;

  const int N = in_sizes[0];   // atom_weights is (N,1)
  const int M = in_sizes[2];   // self_fea_idx is (M,)

  int* row_start = (int*)d_ws; // (N+1) ints

  hipLaunchKernelGGL(build_row_start, dim3((M + 255) / 256), dim3(256), 0,
                     stream, self_idx, row_start, M, N);

  hipLaunchKernelGGL(fused_message_pool, dim3(8192), dim3(64), 0, stream,
                     atom_w, atom_fea, nbr_idx, W1, b1, W2, b2, Wg, bg,
                     row_start, out, N);
}

// Round 2
// 118.042 us; speedup vs baseline: 12.3069x; 12.3069x over previous
//
#include <hip/hip_runtime.h>
#include <math.h>

typedef float f32x4 __attribute__((ext_vector_type(4)));
typedef __bf16 bf16x8 __attribute__((ext_vector_type(8)));

// ---------------------------------------------------------------------------
// CSR row offsets from sorted self_fea_idx. row_start[N] = M.
// ---------------------------------------------------------------------------
__global__ void build_row_start(const int* __restrict__ self_idx,
                                int* __restrict__ row_start, int M, int N) {
  int i = blockIdx.x * blockDim.x + threadIdx.x;
  if (i >= M) return;
  int cur = self_idx[i];
  int prev = (i == 0) ? -1 : self_idx[i - 1];
  for (int j = prev + 1; j <= cur; ++j) row_start[j] = i;
  if (i == M - 1) {
    for (int j = cur + 1; j <= N; ++j) row_start[j] = M;
  }
}

// ---------------------------------------------------------------------------
// Phase A: per-atom precompute of layer-1 halves.
//   U'[a][d] = sum_k X[a][k]*W1[k][d] + b1[d]   (k = 0..63, "self" half)
//   Y [a][d] = sum_k X[a][k]*W1[64+k][d]        ("nbr" half)
// Stored bf16. One wave per 16-atom tile, MFMA 16x16x32.
// A-frag: lane holds A[row=lane&15][k=(lane>>4)*8 + j], j=0..7.
// B-frag: lane holds B[k=(lane>>4)*8 + j][col=lane&15].
// C     : lane holds C[row=(lane>>4)*4 + reg][col=lane&15].
// ---------------------------------------------------------------------------
__global__ __launch_bounds__(64, 2)
void precompute_uy(const float* __restrict__ atom_fea,
                   const float* __restrict__ W1,
                   const float* __restrict__ b1,
                   __bf16* __restrict__ Ub, __bf16* __restrict__ Yb, int N) {
  const int lane = threadIdx.x;
  const int r16 = lane & 15, g = lane >> 4;

  bf16x8 wt[2][4], wb[2][4];
#pragma unroll
  for (int ks = 0; ks < 2; ++ks)
#pragma unroll
    for (int c = 0; c < 4; ++c) {
      bf16x8 t, b;
#pragma unroll
      for (int jj = 0; jj < 8; ++jj) {
        int k = 32 * ks + 8 * g + jj;
        t[jj] = (__bf16)W1[(size_t)k * 64 + 16 * c + r16];
        b[jj] = (__bf16)W1[(size_t)(64 + k) * 64 + 16 * c + r16];
      }
      wt[ks][c] = t; wb[ks][c] = b;
    }
  float b1c[4];
#pragma unroll
  for (int c = 0; c < 4; ++c) b1c[c] = b1[16 * c + r16];

  const int nTiles = (N + 15) >> 4;
  for (int tile = blockIdx.x; tile < nTiles; tile += gridDim.x) {
    const int a0 = tile * 16;
    int arow = a0 + r16; if (arow >= N) arow = N - 1;

    bf16x8 af[2];
#pragma unroll
    for (int ks = 0; ks < 2; ++ks) {
      const float* p = atom_fea + (size_t)arow * 64 + 32 * ks + 8 * g;
      f32x4 x0 = *(const f32x4*)p;
      f32x4 x1 = *(const f32x4*)(p + 4);
      bf16x8 a;
#pragma unroll
      for (int jj = 0; jj < 4; ++jj) { a[jj] = (__bf16)x0[jj]; a[4 + jj] = (__bf16)x1[jj]; }
      af[ks] = a;
    }

    f32x4 uacc[4], yacc[4];
#pragma unroll
    for (int c = 0; c < 4; ++c) { uacc[c] = (f32x4)0.0f; yacc[c] = (f32x4)0.0f; }
#pragma unroll
    for (int ks = 0; ks < 2; ++ks)
#pragma unroll
      for (int c = 0; c < 4; ++c) {
        uacc[c] = __builtin_amdgcn_mfma_f32_16x16x32_bf16(af[ks], wt[ks][c], uacc[c], 0, 0, 0);
        yacc[c] = __builtin_amdgcn_mfma_f32_16x16x32_bf16(af[ks], wb[ks][c], yacc[c], 0, 0, 0);
      }

#pragma unroll
    for (int c = 0; c < 4; ++c)
#pragma unroll
      for (int j = 0; j < 4; ++j) {
        int row = a0 + 4 * g + j;
        if (row < N) {
          Ub[(size_t)row * 64 + 16 * c + r16] = (__bf16)(uacc[c][j] + b1c[c]);
          Yb[(size_t)row * 64 + 16 * c + r16] = (__bf16)yacc[c][j];
        }
      }
  }
}

// ---------------------------------------------------------------------------
// Main fused kernel: one wave per segment, 16-edge MFMA tiles, online softmax.
// No LDS, no barriers. Cross-lane traffic only via shfl.
// ---------------------------------------------------------------------------
__global__ __launch_bounds__(64, 4)
void fused_pool(const float* __restrict__ atom_w,
                const float* __restrict__ atom_fea,
                const int* __restrict__ nbr_idx,
                const float* __restrict__ W2,
                const float* __restrict__ b2,
                const float* __restrict__ Wg,
                const float* __restrict__ bg,
                const int* __restrict__ row_start,
                const __bf16* __restrict__ Ub,
                const __bf16* __restrict__ Yb,
                float* __restrict__ out, int N) {
  const int lane = threadIdx.x;
  const int r16 = lane & 15, g = lane >> 4;

  // W2 B-frags
  bf16x8 w2f[2][4];
#pragma unroll
  for (int ks = 0; ks < 2; ++ks)
#pragma unroll
    for (int c = 0; c < 4; ++c) {
      bf16x8 t;
#pragma unroll
      for (int jj = 0; jj < 8; ++jj) {
        int k = 32 * ks + 8 * g + jj;
        t[jj] = (__bf16)W2[(size_t)k * 64 + 16 * c + r16];
      }
      w2f[ks][c] = t;
    }
  float b2c[4];
#pragma unroll
  for (int c = 0; c < 4; ++c) b2c[c] = b2[16 * c + r16];

  // wg2[k] = sum_d W2[k][d]*Wg[d]  (lane holds k = lane)
  float wgl = 0.f;
  {
    const float* w2row = W2 + (size_t)lane * 64;
#pragma unroll
    for (int d = 0; d < 64; ++d) wgl = fmaf(w2row[d], Wg[d], wgl);
  }
  // bgp = bg + sum_d b2[d]*Wg[d]
  float tb = b2[lane] * Wg[lane];
#pragma unroll
  for (int off = 1; off < 64; off <<= 1) tb += __shfl_xor(tb, off);
  const float bgp = bg[0] + tb;

  // gate B-frag: col 0 = wg2, other cols 0
  bf16x8 wgf[2];
#pragma unroll
  for (int ks = 0; ks < 2; ++ks) {
    bf16x8 t;
#pragma unroll
    for (int jj = 0; jj < 8; ++jj) {
      float v = __shfl(wgl, 32 * ks + 8 * g + jj);
      t[jj] = (r16 == 0) ? (__bf16)v : (__bf16)0.0f;
    }
    wgf[ks] = t;
  }

  for (int s = blockIdx.x; s < N; s += gridDim.x) {
    const int start = row_start[s];
    const int end = row_start[s + 1];

    // u'[k] for this lane's A-frag slots (k = 32ks + 8g + jj)
    float uf[16];
#pragma unroll
    for (int ks = 0; ks < 2; ++ks) {
      const bf16x8 uv = *(const bf16x8*)(Ub + (size_t)s * 64 + 32 * ks + 8 * g);
#pragma unroll
      for (int jj = 0; jj < 8; ++jj) uf[ks * 8 + jj] = (float)uv[jj];
    }

    float m = -INFINITY, ssum = 0.f;
    float accc[4] = {0.f, 0.f, 0.f, 0.f};

    const int nT = (end - start + 15) >> 4;
    for (int t = 0; t < nT; ++t) {
      const int base = start + t * 16;
      const int er = base + r16;
      const int nb = (er < end) ? nbr_idx[er] : 0;
      const float awr = atom_w[nb];

      // H tile directly in A-frag order: H[e][k] = leaky(u'[k] + Y[nb_e][k])
      bf16x8 ah[2];
#pragma unroll
      for (int ks = 0; ks < 2; ++ks) {
        const bf16x8 yv = *(const bf16x8*)(Yb + (size_t)nb * 64 + 32 * ks + 8 * g);
        bf16x8 a;
#pragma unroll
        for (int jj = 0; jj < 8; ++jj) {
          float hf = uf[ks * 8 + jj] + (float)yv[jj];
          hf = fmaxf(hf, 0.01f * hf);          // leaky_relu (slope 0.01)
          a[jj] = (__bf16)hf;
        }
        ah[ks] = a;
      }

      f32x4 facc[4]; f32x4 gacc = (f32x4)0.0f;
#pragma unroll
      for (int c = 0; c < 4; ++c) facc[c] = (f32x4)0.0f;
#pragma unroll
      for (int ks = 0; ks < 2; ++ks) {
#pragma unroll
        for (int c = 0; c < 4; ++c)
          facc[c] = __builtin_amdgcn_mfma_f32_16x16x32_bf16(ah[ks], w2f[ks][c], facc[c], 0, 0, 0);
        gacc = __builtin_amdgcn_mfma_f32_16x16x32_bf16(ah[ks], wgf[ks], gacc, 0, 0, 0);
      }

      // broadcast gates (live in col 0 -> lanes r16==0) and atom weights
      const int gbase = lane & 0x30;
      float gj[4], aw4[4];
#pragma unroll
      for (int j = 0; j < 4; ++j) gj[j] = __shfl(gacc[j], gbase) + bgp;
#pragma unroll
      for (int j = 0; j < 4; ++j) aw4[j] = __shfl(awr, 4 * (lane >> 4) + j);
#pragma unroll
      for (int j = 0; j < 4; ++j) {
        int row = 4 * (lane >> 4) + j;
        if (base + row >= end) gj[j] = -INFINITY;
      }

      float mt = fmaxf(fmaxf(gj[0], gj[1]), fmaxf(gj[2], gj[3]));
      mt = fmaxf(mt, __shfl_xor(mt, 16));
      mt = fmaxf(mt, __shfl_xor(mt, 32));

      const float nm = fmaxf(m, mt);
      const float sc = __expf(m - nm);      // m = -inf first tile -> 0
#pragma unroll
      for (int c = 0; c < 4; ++c) accc[c] *= sc;
      ssum *= sc;

      float wj[4], wsum = 0.f;
#pragma unroll
      for (int j = 0; j < 4; ++j) {
        wj[j] = aw4[j] * __expf(gj[j] - nm);  // -inf rows -> 0
        wsum += wj[j];
      }
      ssum += wsum;
#pragma unroll
      for (int c = 0; c < 4; ++c) {
        float a = accc[c];
#pragma unroll
        for (int j = 0; j < 4; ++j) a = fmaf(wj[j], facc[c][j], a);
        accc[c] = fmaf(b2c[c], wsum, a);     // fold +b2 into F
      }
      m = nm;
    }

    // reduce partial sums across the 4 row-groups
#pragma unroll
    for (int c = 0; c < 4; ++c) {
      accc[c] += __shfl_xor(accc[c], 16);
      accc[c] += __shfl_xor(accc[c], 32);
    }
    ssum += __shfl_xor(ssum, 16);
    ssum += __shfl_xor(ssum, 32);

    // lane's output dim = lane = 16*g + r16 -> chunk c = g
    float val = accc[0];
    val = (g == 1) ? accc[1] : val;
    val = (g == 2) ? accc[2] : val;
    val = (g == 3) ? accc[3] : val;

    out[(size_t)s * 64 + lane] = val / (ssum + 1e-13f) + atom_fea[(size_t)s * 64 + lane];
  }
}

extern "C" void kernel_launch(void* const* d_in, const int* in_sizes, int n_in,
                              void* d_out, int out_size, void* d_ws, size_t ws_size,
                              hipStream_t stream) {
  const float* atom_w   = (const float*)d_in[0];
  const float* atom_fea = (const float*)d_in[1];
  const int*   self_idx = (const int*)d_in[2];
  const int*   nbr_idx  = (const int*)d_in[3];
  const float* W1 = (const float*)d_in[4];
  const float* b1 = (const float*)d_in[5];
  const float* W2 = (const float*)d_in[6];
  const float* b2 = (const float*)d_in[7];
  const float* Wg = (const float*)d_in[8];
  const float* bg = (const float*)d_in[9];
  float* out = (float*)d_out;

  const int N = in_sizes[0];   // atom_weights is (N,1)
  const int M = in_sizes[2];   // self_fea_idx is (M,)

  char* ws = (char*)d_ws;
  int* row_start = (int*)ws;
  size_t off = ((size_t)(N + 1) * sizeof(int) + 255) & ~(size_t)255;
  __bf16* Ub = (__bf16*)(ws + off);
  __bf16* Yb = Ub + (size_t)N * 64;

  hipLaunchKernelGGL(build_row_start, dim3((M + 255) / 256), dim3(256), 0,
                     stream, self_idx, row_start, M, N);
  hipLaunchKernelGGL(precompute_uy, dim3(2048), dim3(64), 0, stream,
                     atom_fea, W1, b1, Ub, Yb, N);
  hipLaunchKernelGGL(fused_pool, dim3(8192), dim3(64), 0, stream,
                     atom_w, atom_fea, nbr_idx, W2, b2, Wg, bg,
                     row_start, Ub, Yb, out, N);
}